// Round 5
// baseline (2453.966 us; speedup 1.0000x reference)
//
#include <hip/hip_runtime.h>

#define N_NODES 100000
#define N_EDGES 1600000
#define D 64
#define NB 131                 // nodes per bucket
#define NBUCKETS 764           // ceil(100000/131)
#define ACC_STRIDE 65          // padded f32 stride per node row
#define LBLK 512

typedef unsigned int u32;
typedef unsigned short u16;
typedef _Float16 f16;
typedef f16 f16x8 __attribute__((ext_vector_type(8)));
typedef float f32x4 __attribute__((ext_vector_type(4)));

// ---------------- fused histogram: per-node count + per-bucket count ----------------
__global__ void histcount_kernel(const int* __restrict__ dst, int* __restrict__ cnt,
                                 int* __restrict__ bcnt) {
    int e = blockIdx.x * blockDim.x + threadIdx.x;
    if (e < N_EDGES) {
        int d = dst[e];
        atomicAdd(&cnt[d], 1);
        atomicAdd(&bcnt[d / NB], 1);
    }
}

// ---------------- scan 764 bucket counts -> bptr[765], bcur copy ----------------
__global__ __launch_bounds__(1024) void bscan_kernel(const int* __restrict__ bcnt,
                                                     int* __restrict__ bptr,
                                                     int* __restrict__ bcur) {
    __shared__ int s[1024];
    int t = threadIdx.x;
    int v = (t < NBUCKETS) ? bcnt[t] : 0;
    s[t] = v;
    __syncthreads();
    for (int off = 1; off < 1024; off <<= 1) {
        int a = (t >= off) ? s[t - off] : 0;
        __syncthreads();
        s[t] += a;
        __syncthreads();
    }
    if (t < NBUCKETS) {
        int excl = s[t] - v;
        bptr[t] = excl;
        bcur[t] = excl;
    }
    if (t == NBUCKETS - 1) bptr[NBUCKETS] = s[t];
}

// ---------------- partition: pairs[pos] = (dl<<24) | src ----------------
__global__ void part_kernel(const int* __restrict__ src, const int* __restrict__ dst,
                            int* __restrict__ bcur, u32* __restrict__ pairs) {
    int e = blockIdx.x * blockDim.x + threadIdx.x;
    if (e < N_EDGES) {
        int s = src[e];
        int d = dst[e];
        int b = d / NB;
        int pos = atomicAdd(&bcur[b], 1);
        pairs[pos] = ((u32)(d - b * NB) << 24) | (u32)s;
    }
}

__global__ void inv_kernel(const int* __restrict__ cnt, float* __restrict__ inv) {
    int n = blockIdx.x * blockDim.x + threadIdx.x;
    if (n < N_NODES) inv[n] = 1.0f / fmaxf((float)cnt[n], 1.0f);
}

// ---------------- f32 -> f16 conversion ----------------
__global__ void tof16_kernel(const float* __restrict__ in, u16* __restrict__ outh, int n4) {
    int i = blockIdx.x * blockDim.x + threadIdx.x;
    if (i < n4) {
        float4 v = reinterpret_cast<const float4*>(in)[i];
        union { f16 h[4]; uint2 u; } cv;
        cv.h[0] = (f16)v.x; cv.h[1] = (f16)v.y; cv.h[2] = (f16)v.z; cv.h[3] = (f16)v.w;
        reinterpret_cast<uint2*>(outh)[i] = cv.u;
    }
}

// ---------------- precompute MFMA B-fragments for all 3 layers ----------------
// Bfrag[layer][f=ktg*4+nt][lane]: lane l holds col o=nt*16+(l&15), k=(ktg&1)*32+(l>>4)*8..+8
// of W = (ktg&2) ? Wr : Wl   (verified layout from R4).
__global__ void prep_bfrag(const float* __restrict__ Wl0, const float* __restrict__ Wr0,
                           const float* __restrict__ Wl1, const float* __restrict__ Wr1,
                           const float* __restrict__ Wl2, const float* __restrict__ Wr2,
                           uint4* __restrict__ Bfrag) {
    int idx = blockIdx.x * blockDim.x + threadIdx.x;
    if (idx >= 3 * 16 * 64) return;
    int layer = idx >> 10, r = idx & 1023, f = r >> 6, l = r & 63;
    const float* Wl = layer == 0 ? Wl0 : layer == 1 ? Wl1 : Wl2;
    const float* Wr = layer == 0 ? Wr0 : layer == 1 ? Wr1 : Wr2;
    int ktg = f >> 2, nt = f & 3;
    const float* W = (ktg & 2) ? Wr : Wl;
    int o = nt * 16 + (l & 15);
    int k = (ktg & 1) * 32 + (l >> 4) * 8;
    const float* s = W + o * 64 + k;
    float4 v0 = *reinterpret_cast<const float4*>(s);
    float4 v1 = *reinterpret_cast<const float4*>(s + 4);
    union { f16x8 h; uint4 u; } cv;
    cv.h[0] = (f16)v0.x; cv.h[1] = (f16)v0.y; cv.h[2] = (f16)v0.z; cv.h[3] = (f16)v0.w;
    cv.h[4] = (f16)v1.x; cv.h[5] = (f16)v1.y; cv.h[6] = (f16)v1.z; cv.h[7] = (f16)v1.w;
    Bfrag[idx] = cv.u;
}

// ---------------- fused SAGE layer: LDS-atomic aggregation + MFMA ----------------
// One block per bucket (131 nodes). 512 threads = 8 waves.
// Edge phase: group of 8 lanes per edge (j8 = channel octet); f16x8 row gather,
// ds_add_f32 into swizzled acc: word(dl,c) = dl*65 + (c&7)*8 + (c>>3)
//   -> edge-phase adds hit stride-1 banks; matmul reads are cheap scalar ds_read.
// Matmul phase: wave w -> 16-node tile(s); A k<64 = mean (LDS acc * inv),
// k>=64 = self row (global); B-fragments from global (precomputed).
__global__ __launch_bounds__(LBLK, 6) void sage_layer(
    const u16* __restrict__ hh, const u32* __restrict__ pairs,
    const int* __restrict__ bptr, const float* __restrict__ inv,
    const uint4* __restrict__ Bfrag, const float* __restrict__ bvec,
    float* __restrict__ outf, u16* __restrict__ outh, int relu)
{
    __shared__ float accs[NB * ACC_STRIDE];   // 34,060 B

    int t = threadIdx.x;
    int b = blockIdx.x;
    int nb0 = b * NB;
    int nnodes = min(NB, N_NODES - nb0);

    for (int i = t; i < NB * ACC_STRIDE; i += LBLK) accs[i] = 0.f;
    __syncthreads();

    int e0 = bptr[b], e1 = bptr[b + 1];
    int j8 = t & 7;          // channel octet
    int sub = t >> 3;        // edge slot 0..63 within block
    const uint4* rows = reinterpret_cast<const uint4*>(hh);

    // ---- edge phase: 128 edges/iter, pair prefetch 1 deep ----
    int base = e0;
    u32 p0 = 0, p1 = 0;
    bool have = (base + 128 <= e1);
    if (have) { p0 = pairs[base + sub]; p1 = pairs[base + 64 + sub]; }
    while (have) {
        uint4 r0 = rows[(p0 & 0xFFFFFFu) * 8 + j8];
        uint4 r1 = rows[(p1 & 0xFFFFFFu) * 8 + j8];
        int nbase = base + 128;
        bool nhave = (nbase + 128 <= e1);
        u32 np0 = 0, np1 = 0;
        if (nhave) { np0 = pairs[nbase + sub]; np1 = pairs[nbase + 64 + sub]; }
        float* A0 = &accs[(int)(p0 >> 24) * ACC_STRIDE + j8];
        float* A1 = &accs[(int)(p1 >> 24) * ACC_STRIDE + j8];
        union { uint4 u; f16x8 h; } c0, c1;
        c0.u = r0; c1.u = r1;
        #pragma unroll
        for (int i = 0; i < 8; ++i) atomicAdd(&A0[i * 8], (float)c0.h[i]);
        #pragma unroll
        for (int i = 0; i < 8; ++i) atomicAdd(&A1[i * 8], (float)c1.h[i]);
        p0 = np0; p1 = np1; base = nbase; have = nhave;
    }
    for (int e = base + sub; e < e1; e += 64) {
        u32 p = pairs[e];
        uint4 r = rows[(p & 0xFFFFFFu) * 8 + j8];
        float* A = &accs[(int)(p >> 24) * ACC_STRIDE + j8];
        union { uint4 u; f16x8 h; } cv; cv.u = r;
        #pragma unroll
        for (int i = 0; i < 8; ++i) atomicAdd(&A[i * 8], (float)cv.h[i]);
    }
    __syncthreads();

    // ---- matmul phase: tiles of 16 nodes; wave w -> tile w (+ tile 8 for wave 0) ----
    int w = t >> 6, lane = t & 63;
    int row = lane & 15, kg = lane >> 4;

    for (int tile = w; tile * 16 < nnodes; tile += 8) {
        int dl = tile * 16 + row;
        int dlc = min(dl, NB - 1);
        int node = nb0 + dl;
        int nodec = min(node, N_NODES - 1);
        float sinv = inv[nodec];

        f32x4 acc[4] = {};
        #pragma unroll
        for (int ktg = 0; ktg < 2; ++ktg) {          // mean part, k 0..63
            union { f16x8 h; uint4 u; } av;
            int wbase = dlc * ACC_STRIDE + (ktg * 4 + kg);
            #pragma unroll
            for (int i = 0; i < 8; ++i) av.h[i] = (f16)(accs[wbase + i * 8] * sinv);
            #pragma unroll
            for (int nt = 0; nt < 4; ++nt) {
                union { uint4 u; f16x8 h; } bv; bv.u = Bfrag[(ktg * 4 + nt) * 64 + lane];
                acc[nt] = __builtin_amdgcn_mfma_f32_16x16x32_f16(av.h, bv.h, acc[nt], 0, 0, 0);
            }
        }
        #pragma unroll
        for (int ktg = 2; ktg < 4; ++ktg) {          // self part, k 64..127
            union { f16x8 h; uint4 u; } av;
            av.u = rows[(long long)nodec * 8 + (ktg - 2) * 4 + kg];
            #pragma unroll
            for (int nt = 0; nt < 4; ++nt) {
                union { uint4 u; f16x8 h; } bv; bv.u = Bfrag[(ktg * 4 + nt) * 64 + lane];
                acc[nt] = __builtin_amdgcn_mfma_f32_16x16x32_f16(av.h, bv.h, acc[nt], 0, 0, 0);
            }
        }

        // epilogue: C col=lane&15 (=out channel via nt*16+row), row=(lane>>4)*4+r (=node)
        #pragma unroll
        for (int nt = 0; nt < 4; ++nt) {
            int o = nt * 16 + row;
            float bia = bvec[o];
            #pragma unroll
            for (int r = 0; r < 4; ++r) {
                int n_out = tile * 16 + kg * 4 + r;
                if (n_out < nnodes) {
                    int node_out = nb0 + n_out;
                    float vout = acc[nt][r] + bia;
                    if (relu) vout = fmaxf(vout, 0.f);
                    if (outf) outf[(long long)node_out * D + o] = vout;
                    if (outh) {
                        union { f16 h; u16 u; } cv; cv.h = (f16)vout;
                        outh[(long long)node_out * D + o] = cv.u;
                    }
                }
            }
        }
    }
}

extern "C" void kernel_launch(void* const* d_in, const int* in_sizes, int n_in,
                              void* d_out, int out_size, void* d_ws, size_t ws_size,
                              hipStream_t stream) {
    const float* x   = (const float*)d_in[0];
    const int*   ei  = (const int*)d_in[1];
    const int*   src = ei;
    const int*   dst = ei + N_EDGES;
    const float* Wl0 = (const float*)d_in[2];
    const float* Wr0 = (const float*)d_in[3];
    const float* b0  = (const float*)d_in[4];
    const float* Wl1 = (const float*)d_in[5];
    const float* Wr1 = (const float*)d_in[6];
    const float* b1  = (const float*)d_in[7];
    const float* Wl2 = (const float*)d_in[8];
    const float* Wr2 = (const float*)d_in[9];
    const float* b2  = (const float*)d_in[10];
    float* out = (float*)d_out;

    // ---- workspace layout (256B-aligned regions) ----
    char* p = (char*)d_ws;
    auto take = [&](size_t bytes) { char* r = p; p += (bytes + 255) & ~(size_t)255; return r; };
    int*   cnt   = (int*)take((size_t)N_NODES * 4);
    int*   bcnt  = (int*)take((size_t)NBUCKETS * 4);
    int*   bptr  = (int*)take((size_t)(NBUCKETS + 1) * 4);
    int*   bcur  = (int*)take((size_t)NBUCKETS * 4);
    u32*   pairs = (u32*)take((size_t)N_EDGES * 4);
    float* inv   = (float*)take((size_t)N_NODES * 4);
    uint4* Bfrag = (uint4*)take((size_t)3 * 16 * 64 * 16);
    u16*   xh    = (u16*)take((size_t)N_NODES * D * 2);
    u16*   h0h   = (u16*)take((size_t)N_NODES * D * 2);
    u16*   h1h   = (u16*)take((size_t)N_NODES * D * 2);

    const int BLK = 256;
    const int edge_grid = (N_EDGES + BLK - 1) / BLK;
    const int node_grid = (N_NODES + BLK - 1) / BLK;
    const int conv_grid = (N_NODES * D / 4 + BLK - 1) / BLK;

    // ---- bucketed edge partition (graph is layer-invariant; once per call) ----
    hipMemsetAsync(cnt, 0, (size_t)N_NODES * sizeof(int), stream);
    hipMemsetAsync(bcnt, 0, (size_t)NBUCKETS * sizeof(int), stream);
    histcount_kernel<<<edge_grid, BLK, 0, stream>>>(dst, cnt, bcnt);
    bscan_kernel<<<1, 1024, 0, stream>>>(bcnt, bptr, bcur);
    inv_kernel<<<node_grid, BLK, 0, stream>>>(cnt, inv);
    part_kernel<<<edge_grid, BLK, 0, stream>>>(src, dst, bcur, pairs);
    tof16_kernel<<<conv_grid, BLK, 0, stream>>>(x, xh, N_NODES * D / 4);
    prep_bfrag<<<(3 * 1024 + BLK - 1) / BLK, BLK, 0, stream>>>(Wl0, Wr0, Wl1, Wr1, Wl2, Wr2, Bfrag);

    // ---- 3 fused layers ----
    sage_layer<<<NBUCKETS, LBLK, 0, stream>>>(xh,  pairs, bptr, inv, Bfrag,          b0, nullptr, h0h, 1);
    sage_layer<<<NBUCKETS, LBLK, 0, stream>>>(h0h, pairs, bptr, inv, Bfrag + 1024,   b1, nullptr, h1h, 1);
    sage_layer<<<NBUCKETS, LBLK, 0, stream>>>(h1h, pairs, bptr, inv, Bfrag + 2048,   b2, out, nullptr, 0);
}

// Round 6
// 1038.552 us; speedup vs baseline: 2.3629x; 2.3629x over previous
//
#include <hip/hip_runtime.h>

#define N_NODES 100000
#define N_EDGES 1600000
#define D 64
#define NB 131                 // nodes per bucket
#define NBUCKETS 764           // ceil(100000/131)

typedef unsigned int u32;
typedef unsigned short u16;
typedef _Float16 f16;
typedef f16 f16x8 __attribute__((ext_vector_type(8)));
typedef float f32x4 __attribute__((ext_vector_type(4)));

// ---------------- bucket histogram (764 counters, int atomics) ----------------
__global__ void bcount_kernel(const int* __restrict__ dst, int* __restrict__ bcnt) {
    int e = blockIdx.x * blockDim.x + threadIdx.x;
    if (e < N_EDGES) atomicAdd(&bcnt[dst[e] / NB], 1);
}

// ---------------- scan 764 bucket counts -> bptr[765], bcur copy ----------------
__global__ __launch_bounds__(1024) void bscan_kernel(const int* __restrict__ bcnt,
                                                     int* __restrict__ bptr,
                                                     int* __restrict__ bcur) {
    __shared__ int s[1024];
    int t = threadIdx.x;
    int v = (t < NBUCKETS) ? bcnt[t] : 0;
    s[t] = v;
    __syncthreads();
    for (int off = 1; off < 1024; off <<= 1) {
        int a = (t >= off) ? s[t - off] : 0;
        __syncthreads();
        s[t] += a;
        __syncthreads();
    }
    if (t < NBUCKETS) {
        int excl = s[t] - v;
        bptr[t] = excl;
        bcur[t] = excl;
    }
    if (t == NBUCKETS - 1) bptr[NBUCKETS] = s[t];
}

// ---------------- partition: pairs[pos] = (dl<<24) | src (frontier writes coalesce in L2) ----
__global__ void part_kernel(const int* __restrict__ src, const int* __restrict__ dst,
                            int* __restrict__ bcur, u32* __restrict__ pairs) {
    int e = blockIdx.x * blockDim.x + threadIdx.x;
    if (e < N_EDGES) {
        int s = src[e];
        int d = dst[e];
        int b = d / NB;
        int pos = atomicAdd(&bcur[b], 1);
        pairs[pos] = ((u32)(d - b * NB) << 24) | (u32)s;
    }
}

// ---------------- per-bucket local CSR: histogram -> scan -> fill ----------------
// One block per bucket. All atomics are INT LDS atomics (native ds ops).
// csr_src writes land inside the bucket's contiguous window -> L2-coalesced lines.
__global__ __launch_bounds__(256) void local_csr_kernel(
    const u32* __restrict__ pairs, const int* __restrict__ bptr,
    int* __restrict__ row_ptr, int* __restrict__ cnt, float* __restrict__ inv,
    int* __restrict__ csr_src)
{
    __shared__ int lcnt[NB];
    __shared__ int lofs[NB];
    __shared__ int s[256];

    int t = threadIdx.x, b = blockIdx.x;
    int e0 = bptr[b], e1 = bptr[b + 1];
    int nb0 = b * NB;

    for (int i = t; i < NB; i += 256) lcnt[i] = 0;
    __syncthreads();
    for (int e = e0 + t; e < e1; e += 256) atomicAdd(&lcnt[pairs[e] >> 24], 1);
    __syncthreads();

    // Hillis-Steele inclusive scan over 256 slots (NB=131 padded)
    int v = (t < NB) ? lcnt[t] : 0;
    s[t] = v;
    __syncthreads();
    for (int off = 1; off < 256; off <<= 1) {
        int a = (t >= off) ? s[t - off] : 0;
        __syncthreads();
        s[t] += a;
        __syncthreads();
    }
    if (t < NB) {
        int node = nb0 + t;
        if (node < N_NODES) {
            int excl = s[t] - v;
            lofs[t] = excl;
            row_ptr[node] = e0 + excl;
            cnt[node] = v;
            inv[node] = 1.0f / fmaxf((float)v, 1.0f);
        }
        lcnt[t] = 0;   // reuse as fill cursor
    }
    __syncthreads();
    for (int e = e0 + t; e < e1; e += 256) {
        u32 p = pairs[e];
        int dl = (int)(p >> 24);
        int pos = atomicAdd(&lcnt[dl], 1);
        csr_src[e0 + lofs[dl] + pos] = (int)(p & 0xFFFFFFu);
    }
}

// ---------------- f32 -> f16 conversion (4 elems/thread) ----------------
__global__ void tof16_kernel(const float* __restrict__ in, u16* __restrict__ outh, int n4) {
    int i = blockIdx.x * blockDim.x + threadIdx.x;
    if (i < n4) {
        float4 v = reinterpret_cast<const float4*>(in)[i];
        union { f16 h[4]; uint2 u; } cv;
        cv.h[0] = (f16)v.x; cv.h[1] = (f16)v.y; cv.h[2] = (f16)v.z; cv.h[3] = (f16)v.w;
        reinterpret_cast<uint2*>(outh)[i] = cv.u;
    }
}

__device__ __forceinline__ void add8(float* va, uint4 r) {
    union { uint4 u; f16x8 h; } cv; cv.u = r;
    #pragma unroll
    for (int e = 0; e < 8; ++e) va[e] += (float)cv.h[e];
}

// ---------------- fused SAGE layer (MFMA) — identical to R4 (verified) ----------------
__global__ __launch_bounds__(256, 4) void sage_layer(
    const u16* __restrict__ hh,        // f16 features [N][64]
    const int* __restrict__ row_ptr, const int* __restrict__ cnt,
    const int* __restrict__ csr_src, const float* __restrict__ inv,
    const float* __restrict__ Wl, const float* __restrict__ Wr,
    const float* __restrict__ bvec,
    float* __restrict__ outf,          // f32 output (nullptr to skip)
    u16* __restrict__ outh,            // f16 output (nullptr to skip)
    int relu)
{
    __shared__ uint4 Blds[16 * 64];        // 16 fragments x 64 lanes x 16B
    __shared__ u16 Atile[4][16][128];      // per-wave swizzled A

    int t = threadIdx.x;

    // ---- arrange B fragments: frag f=(ktg*4+nt): lane l elem e = W[o=nt*16+(l&15)][k]
    for (int idx = t; idx < 16 * 64; idx += 256) {
        int f = idx >> 6, l = idx & 63;
        int ktg = f >> 2, nt = f & 3;
        const float* W = (ktg & 2) ? Wr : Wl;
        int o = nt * 16 + (l & 15);
        int k = (ktg & 1) * 32 + (l >> 4) * 8;
        const float* s = W + o * 64 + k;
        float4 v0 = *reinterpret_cast<const float4*>(s);
        float4 v1 = *reinterpret_cast<const float4*>(s + 4);
        union { f16x8 h; uint4 u; } cv;
        cv.h[0] = (f16)v0.x; cv.h[1] = (f16)v0.y; cv.h[2] = (f16)v0.z; cv.h[3] = (f16)v0.w;
        cv.h[4] = (f16)v1.x; cv.h[5] = (f16)v1.y; cv.h[6] = (f16)v1.z; cv.h[7] = (f16)v1.w;
        Blds[idx] = cv.u;
    }
    __syncthreads();

    int w    = t >> 6;
    int lane = t & 63;
    int j8   = lane & 7;    // channel octet within row / row-lane
    int sub  = lane >> 3;   // edge subgroup 0..7
    const uint4* rows = reinterpret_cast<const uint4*>(hh);   // 8 x uint4 per node

    int base = blockIdx.x * 64 + w * 16;

    float bias[4];
    #pragma unroll
    for (int nt = 0; nt < 4; ++nt) bias[nt] = bvec[nt * 16 + (lane & 15)];

    // ---- gather 16 nodes into A-tile ----
    for (int n = 0; n < 16; ++n) {
        int node = base + n;
        if (node >= N_NODES) break;             // wave-uniform
        uint4 selfrow = rows[node * 8 + j8];    // in flight during gather
        int s0 = row_ptr[node];
        int c  = cnt[node];
        float va[8] = {0.f,0.f,0.f,0.f,0.f,0.f,0.f,0.f};
        int j = 0;
        for (; j + 16 <= c; j += 16) {
            int i0 = csr_src[s0 + j + sub];
            int i1 = csr_src[s0 + j + 8 + sub];
            uint4 r0 = rows[i0 * 8 + j8];
            uint4 r1 = rows[i1 * 8 + j8];
            add8(va, r0);
            add8(va, r1);
        }
        for (; j + 8 <= c; j += 8) {
            int i0 = csr_src[s0 + j + sub];
            uint4 r0 = rows[i0 * 8 + j8];
            add8(va, r0);
        }
        int rem = c - j;
        if (sub < rem) {
            int i0 = csr_src[s0 + j + sub];
            uint4 r0 = rows[i0 * 8 + j8];
            add8(va, r0);
        }
        // butterfly reduce over the 8 edge-subgroups
        #pragma unroll
        for (int e = 0; e < 8; ++e) {
            va[e] += __shfl_xor(va[e], 8);
            va[e] += __shfl_xor(va[e], 16);
            va[e] += __shfl_xor(va[e], 32);
        }
        int chunk = j8 ^ (n & 7);
        if (lane < 8) {                 // mean -> k 0..63
            float sc = inv[node];
            union { f16x8 h; uint4 u; } cv;
            #pragma unroll
            for (int e = 0; e < 8; ++e) cv.h[e] = (f16)(va[e] * sc);
            *reinterpret_cast<uint4*>(&Atile[w][n][chunk * 8]) = cv.u;
        } else if (lane < 16) {         // self -> k 64..127
            *reinterpret_cast<uint4*>(&Atile[w][n][64 + chunk * 8]) = selfrow;
        }
    }

    // ---- fragment reads + 16 MFMAs ----
    f32x4 acc[4] = {};
    int row = lane & 15, kg = lane >> 4;
    #pragma unroll
    for (int ktg = 0; ktg < 4; ++ktg) {
        int idx16 = ktg * 4 + kg;
        int swz = (idx16 & 8) | ((idx16 & 7) ^ (row & 7));
        uint4 a = *reinterpret_cast<const uint4*>(&Atile[w][row][swz * 8]);
        union { uint4 u; f16x8 h; } av; av.u = a;
        #pragma unroll
        for (int nt = 0; nt < 4; ++nt) {
            union { uint4 u; f16x8 h; } bv; bv.u = Blds[(ktg * 4 + nt) * 64 + lane];
            acc[nt] = __builtin_amdgcn_mfma_f32_16x16x32_f16(av.h, bv.h, acc[nt], 0, 0, 0);
        }
    }

    // ---- epilogue: bias (+ReLU), stores. C: col=lane&15, row=(lane>>4)*4+reg ----
    #pragma unroll
    for (int nt = 0; nt < 4; ++nt) {
        int o = nt * 16 + (lane & 15);
        #pragma unroll
        for (int r = 0; r < 4; ++r) {
            int n = kg * 4 + r;
            int node = base + n;
            if (node < N_NODES) {
                float vout = acc[nt][r] + bias[nt];
                if (relu) vout = fmaxf(vout, 0.f);
                if (outf) outf[node * 64 + o] = vout;
                if (outh) {
                    union { f16 h; u16 u; } cv; cv.h = (f16)vout;
                    outh[node * 64 + o] = cv.u;
                }
            }
        }
    }
}

extern "C" void kernel_launch(void* const* d_in, const int* in_sizes, int n_in,
                              void* d_out, int out_size, void* d_ws, size_t ws_size,
                              hipStream_t stream) {
    const float* x   = (const float*)d_in[0];
    const int*   ei  = (const int*)d_in[1];
    const int*   src = ei;
    const int*   dst = ei + N_EDGES;
    const float* Wl0 = (const float*)d_in[2];
    const float* Wr0 = (const float*)d_in[3];
    const float* b0  = (const float*)d_in[4];
    const float* Wl1 = (const float*)d_in[5];
    const float* Wr1 = (const float*)d_in[6];
    const float* b1  = (const float*)d_in[7];
    const float* Wl2 = (const float*)d_in[8];
    const float* Wr2 = (const float*)d_in[9];
    const float* b2  = (const float*)d_in[10];
    float* out = (float*)d_out;

    // ---- workspace layout (256B-aligned regions) ----
    char* p = (char*)d_ws;
    auto take = [&](size_t bytes) { char* r = p; p += (bytes + 255) & ~(size_t)255; return r; };
    int*   bcnt    = (int*)take((size_t)NBUCKETS * 4);
    int*   bptr    = (int*)take((size_t)(NBUCKETS + 1) * 4);
    int*   bcur    = (int*)take((size_t)NBUCKETS * 4);
    u32*   pairs   = (u32*)take((size_t)N_EDGES * 4);
    int*   csr_src = (int*)take((size_t)N_EDGES * 4);
    int*   row_ptr = (int*)take((size_t)N_NODES * 4);
    int*   cnt     = (int*)take((size_t)N_NODES * 4);
    float* inv     = (float*)take((size_t)N_NODES * 4);
    u16*   xh      = (u16*)take((size_t)N_NODES * D * 2);
    u16*   h0h     = (u16*)take((size_t)N_NODES * D * 2);
    u16*   h1h     = (u16*)take((size_t)N_NODES * D * 2);

    const int BLK = 256;
    const int edge_grid  = (N_EDGES + BLK - 1) / BLK;
    const int conv_grid  = (N_NODES * D / 4 + BLK - 1) / BLK;
    const int layer_grid = (N_NODES + 63) / 64;    // 64 nodes per block

    // ---- bucketed CSR build (graph is layer-invariant; once per call) ----
    hipMemsetAsync(bcnt, 0, (size_t)NBUCKETS * sizeof(int), stream);
    bcount_kernel<<<edge_grid, BLK, 0, stream>>>(dst, bcnt);
    bscan_kernel<<<1, 1024, 0, stream>>>(bcnt, bptr, bcur);
    part_kernel<<<edge_grid, BLK, 0, stream>>>(src, dst, bcur, pairs);
    local_csr_kernel<<<NBUCKETS, BLK, 0, stream>>>(pairs, bptr, row_ptr, cnt, inv, csr_src);
    tof16_kernel<<<conv_grid, BLK, 0, stream>>>(x, xh, N_NODES * D / 4);

    // ---- 3 fused layers (intermediates are f16-only) ----
    sage_layer<<<layer_grid, BLK, 0, stream>>>(xh,  row_ptr, cnt, csr_src, inv, Wl0, Wr0, b0, nullptr, h0h, 1);
    sage_layer<<<layer_grid, BLK, 0, stream>>>(h0h, row_ptr, cnt, csr_src, inv, Wl1, Wr1, b1, nullptr, h1h, 1);
    sage_layer<<<layer_grid, BLK, 0, stream>>>(h1h, row_ptr, cnt, csr_src, inv, Wl2, Wr2, b2, out, nullptr, 0);
}

// Round 7
// 307.012 us; speedup vs baseline: 7.9931x; 3.3828x over previous
//
#include <hip/hip_runtime.h>

#define N_NODES 100000
#define N_EDGES 1600000
#define D 64
#define NB 131                 // nodes per bucket
#define NBUCKETS 764           // ceil(100000/131)
#define PCHUNK 8192            // edges per partition chunk
#define NCHUNK 196             // ceil(N_EDGES / PCHUNK)
#define PBLK 1024

typedef unsigned int u32;
typedef unsigned short u16;
typedef _Float16 f16;
typedef f16 f16x8 __attribute__((ext_vector_type(8)));
typedef float f32x4 __attribute__((ext_vector_type(4)));

// ---------------- pass 1: per-chunk bucket histogram (LDS atomics only) ----------------
__global__ __launch_bounds__(PBLK) void hist_kernel(const int* __restrict__ dst,
                                                    int* __restrict__ hist) {
    __shared__ int hcnt[NBUCKETS];
    int t = threadIdx.x;
    int c0 = blockIdx.x * PCHUNK;
    int nloc = min(PCHUNK, N_EDGES - c0);
    for (int i = t; i < NBUCKETS; i += PBLK) hcnt[i] = 0;
    __syncthreads();
    for (int i = t; i < nloc; i += PBLK) atomicAdd(&hcnt[dst[c0 + i] / NB], 1);
    __syncthreads();
    for (int i = t; i < NBUCKETS; i += PBLK) hist[blockIdx.x * NBUCKETS + i] = hcnt[i];
}

// ---------------- pass 2: column sums -> bptr; rewrite hist as chunk base offsets ----------------
__global__ __launch_bounds__(1024) void cscan_kernel(int* __restrict__ hist,
                                                     int* __restrict__ bptr) {
    __shared__ int s[1024];
    int t = threadIdx.x;
    int tot = 0;
    if (t < NBUCKETS)
        for (int c = 0; c < NCHUNK; ++c) tot += hist[c * NBUCKETS + t];
    s[t] = tot;
    __syncthreads();
    for (int off = 1; off < 1024; off <<= 1) {
        int a = (t >= off) ? s[t - off] : 0;
        __syncthreads();
        s[t] += a;
        __syncthreads();
    }
    if (t < NBUCKETS) {
        int run = s[t] - tot;          // exclusive prefix over buckets
        bptr[t] = run;
        for (int c = 0; c < NCHUNK; ++c) {
            int v = hist[c * NBUCKETS + t];
            hist[c * NBUCKETS + t] = run;
            run += v;
        }
    }
    if (t == NBUCKETS - 1) bptr[NBUCKETS] = s[t];
}

// ---------------- pass 3: partition (zero global atomics) ----------------
// pairs[pos] = (dl<<24) | src; pos = chunk-bucket base + LDS rank.
__global__ __launch_bounds__(PBLK) void part_kernel(const int* __restrict__ src,
                                                    const int* __restrict__ dst,
                                                    const int* __restrict__ cbase,
                                                    u32* __restrict__ pairs) {
    __shared__ int hcur[NBUCKETS];
    __shared__ int hb[NBUCKETS];
    int t = threadIdx.x;
    int c0 = blockIdx.x * PCHUNK;
    int nloc = min(PCHUNK, N_EDGES - c0);
    for (int i = t; i < NBUCKETS; i += PBLK) {
        hcur[i] = 0;
        hb[i] = cbase[blockIdx.x * NBUCKETS + i];
    }
    __syncthreads();
    for (int i = t; i < nloc; i += PBLK) {
        int s = src[c0 + i];
        int d = dst[c0 + i];
        int b = d / NB;
        int r = atomicAdd(&hcur[b], 1);
        pairs[hb[b] + r] = ((u32)(d - b * NB) << 24) | (u32)s;
    }
}

// ---------------- per-bucket local CSR: histogram -> scan -> fill (unchanged, R6-verified) ----
__global__ __launch_bounds__(256) void local_csr_kernel(
    const u32* __restrict__ pairs, const int* __restrict__ bptr,
    int* __restrict__ row_ptr, int* __restrict__ cnt, float* __restrict__ inv,
    int* __restrict__ csr_src)
{
    __shared__ int lcnt[NB];
    __shared__ int lofs[NB];
    __shared__ int s[256];

    int t = threadIdx.x, b = blockIdx.x;
    int e0 = bptr[b], e1 = bptr[b + 1];
    int nb0 = b * NB;

    for (int i = t; i < NB; i += 256) lcnt[i] = 0;
    __syncthreads();
    for (int e = e0 + t; e < e1; e += 256) atomicAdd(&lcnt[pairs[e] >> 24], 1);
    __syncthreads();

    int v = (t < NB) ? lcnt[t] : 0;
    s[t] = v;
    __syncthreads();
    for (int off = 1; off < 256; off <<= 1) {
        int a = (t >= off) ? s[t - off] : 0;
        __syncthreads();
        s[t] += a;
        __syncthreads();
    }
    if (t < NB) {
        int node = nb0 + t;
        if (node < N_NODES) {
            int excl = s[t] - v;
            lofs[t] = excl;
            row_ptr[node] = e0 + excl;
            cnt[node] = v;
            inv[node] = 1.0f / fmaxf((float)v, 1.0f);
        }
        lcnt[t] = 0;   // reuse as fill cursor
    }
    __syncthreads();
    for (int e = e0 + t; e < e1; e += 256) {
        u32 p = pairs[e];
        int dl = (int)(p >> 24);
        int pos = atomicAdd(&lcnt[dl], 1);
        csr_src[e0 + lofs[dl] + pos] = (int)(p & 0xFFFFFFu);
    }
}

// ---------------- f32 -> f16 conversion (4 elems/thread) ----------------
__global__ void tof16_kernel(const float* __restrict__ in, u16* __restrict__ outh, int n4) {
    int i = blockIdx.x * blockDim.x + threadIdx.x;
    if (i < n4) {
        float4 v = reinterpret_cast<const float4*>(in)[i];
        union { f16 h[4]; uint2 u; } cv;
        cv.h[0] = (f16)v.x; cv.h[1] = (f16)v.y; cv.h[2] = (f16)v.z; cv.h[3] = (f16)v.w;
        reinterpret_cast<uint2*>(outh)[i] = cv.u;
    }
}

__device__ __forceinline__ void add8(float* va, uint4 r) {
    union { uint4 u; f16x8 h; } cv; cv.u = r;
    #pragma unroll
    for (int e = 0; e < 8; ++e) va[e] += (float)cv.h[e];
}

// ---------------- fused SAGE layer (MFMA) — identical to R4 (verified) ----------------
__global__ __launch_bounds__(256, 4) void sage_layer(
    const u16* __restrict__ hh,        // f16 features [N][64]
    const int* __restrict__ row_ptr, const int* __restrict__ cnt,
    const int* __restrict__ csr_src, const float* __restrict__ inv,
    const float* __restrict__ Wl, const float* __restrict__ Wr,
    const float* __restrict__ bvec,
    float* __restrict__ outf,          // f32 output (nullptr to skip)
    u16* __restrict__ outh,            // f16 output (nullptr to skip)
    int relu)
{
    __shared__ uint4 Blds[16 * 64];        // 16 fragments x 64 lanes x 16B
    __shared__ u16 Atile[4][16][128];      // per-wave swizzled A

    int t = threadIdx.x;

    // ---- arrange B fragments: frag f=(ktg*4+nt): lane l elem e = W[o=nt*16+(l&15)][k]
    for (int idx = t; idx < 16 * 64; idx += 256) {
        int f = idx >> 6, l = idx & 63;
        int ktg = f >> 2, nt = f & 3;
        const float* W = (ktg & 2) ? Wr : Wl;
        int o = nt * 16 + (l & 15);
        int k = (ktg & 1) * 32 + (l >> 4) * 8;
        const float* s = W + o * 64 + k;
        float4 v0 = *reinterpret_cast<const float4*>(s);
        float4 v1 = *reinterpret_cast<const float4*>(s + 4);
        union { f16x8 h; uint4 u; } cv;
        cv.h[0] = (f16)v0.x; cv.h[1] = (f16)v0.y; cv.h[2] = (f16)v0.z; cv.h[3] = (f16)v0.w;
        cv.h[4] = (f16)v1.x; cv.h[5] = (f16)v1.y; cv.h[6] = (f16)v1.z; cv.h[7] = (f16)v1.w;
        Blds[idx] = cv.u;
    }
    __syncthreads();

    int w    = t >> 6;
    int lane = t & 63;
    int j8   = lane & 7;    // channel octet within row / row-lane
    int sub  = lane >> 3;   // edge subgroup 0..7
    const uint4* rows = reinterpret_cast<const uint4*>(hh);   // 8 x uint4 per node

    int base = blockIdx.x * 64 + w * 16;

    float bias[4];
    #pragma unroll
    for (int nt = 0; nt < 4; ++nt) bias[nt] = bvec[nt * 16 + (lane & 15)];

    // ---- gather 16 nodes into A-tile ----
    for (int n = 0; n < 16; ++n) {
        int node = base + n;
        if (node >= N_NODES) break;             // wave-uniform
        uint4 selfrow = rows[node * 8 + j8];    // in flight during gather
        int s0 = row_ptr[node];
        int c  = cnt[node];
        float va[8] = {0.f,0.f,0.f,0.f,0.f,0.f,0.f,0.f};
        int j = 0;
        for (; j + 16 <= c; j += 16) {
            int i0 = csr_src[s0 + j + sub];
            int i1 = csr_src[s0 + j + 8 + sub];
            uint4 r0 = rows[i0 * 8 + j8];
            uint4 r1 = rows[i1 * 8 + j8];
            add8(va, r0);
            add8(va, r1);
        }
        for (; j + 8 <= c; j += 8) {
            int i0 = csr_src[s0 + j + sub];
            uint4 r0 = rows[i0 * 8 + j8];
            add8(va, r0);
        }
        int rem = c - j;
        if (sub < rem) {
            int i0 = csr_src[s0 + j + sub];
            uint4 r0 = rows[i0 * 8 + j8];
            add8(va, r0);
        }
        // butterfly reduce over the 8 edge-subgroups
        #pragma unroll
        for (int e = 0; e < 8; ++e) {
            va[e] += __shfl_xor(va[e], 8);
            va[e] += __shfl_xor(va[e], 16);
            va[e] += __shfl_xor(va[e], 32);
        }
        int chunk = j8 ^ (n & 7);
        if (lane < 8) {                 // mean -> k 0..63
            float sc = inv[node];
            union { f16x8 h; uint4 u; } cv;
            #pragma unroll
            for (int e = 0; e < 8; ++e) cv.h[e] = (f16)(va[e] * sc);
            *reinterpret_cast<uint4*>(&Atile[w][n][chunk * 8]) = cv.u;
        } else if (lane < 16) {         // self -> k 64..127
            *reinterpret_cast<uint4*>(&Atile[w][n][64 + chunk * 8]) = selfrow;
        }
    }

    // ---- fragment reads + 16 MFMAs ----
    f32x4 acc[4] = {};
    int row = lane & 15, kg = lane >> 4;
    #pragma unroll
    for (int ktg = 0; ktg < 4; ++ktg) {
        int idx16 = ktg * 4 + kg;
        int swz = (idx16 & 8) | ((idx16 & 7) ^ (row & 7));
        uint4 a = *reinterpret_cast<const uint4*>(&Atile[w][row][swz * 8]);
        union { uint4 u; f16x8 h; } av; av.u = a;
        #pragma unroll
        for (int nt = 0; nt < 4; ++nt) {
            union { uint4 u; f16x8 h; } bv; bv.u = Blds[(ktg * 4 + nt) * 64 + lane];
            acc[nt] = __builtin_amdgcn_mfma_f32_16x16x32_f16(av.h, bv.h, acc[nt], 0, 0, 0);
        }
    }

    // ---- epilogue: bias (+ReLU), stores. C: col=lane&15, row=(lane>>4)*4+reg ----
    #pragma unroll
    for (int nt = 0; nt < 4; ++nt) {
        int o = nt * 16 + (lane & 15);
        #pragma unroll
        for (int r = 0; r < 4; ++r) {
            int n = kg * 4 + r;
            int node = base + n;
            if (node < N_NODES) {
                float vout = acc[nt][r] + bias[nt];
                if (relu) vout = fmaxf(vout, 0.f);
                if (outf) outf[node * 64 + o] = vout;
                if (outh) {
                    union { f16 h; u16 u; } cv; cv.h = (f16)vout;
                    outh[node * 64 + o] = cv.u;
                }
            }
        }
    }
}

extern "C" void kernel_launch(void* const* d_in, const int* in_sizes, int n_in,
                              void* d_out, int out_size, void* d_ws, size_t ws_size,
                              hipStream_t stream) {
    const float* x   = (const float*)d_in[0];
    const int*   ei  = (const int*)d_in[1];
    const int*   src = ei;
    const int*   dst = ei + N_EDGES;
    const float* Wl0 = (const float*)d_in[2];
    const float* Wr0 = (const float*)d_in[3];
    const float* b0  = (const float*)d_in[4];
    const float* Wl1 = (const float*)d_in[5];
    const float* Wr1 = (const float*)d_in[6];
    const float* b1  = (const float*)d_in[7];
    const float* Wl2 = (const float*)d_in[8];
    const float* Wr2 = (const float*)d_in[9];
    const float* b2  = (const float*)d_in[10];
    float* out = (float*)d_out;

    // ---- workspace layout (256B-aligned regions) ----
    char* p = (char*)d_ws;
    auto take = [&](size_t bytes) { char* r = p; p += (bytes + 255) & ~(size_t)255; return r; };
    int*   hist    = (int*)take((size_t)NCHUNK * NBUCKETS * 4);
    int*   bptr    = (int*)take((size_t)(NBUCKETS + 1) * 4);
    u32*   pairs   = (u32*)take((size_t)N_EDGES * 4);
    int*   csr_src = (int*)take((size_t)N_EDGES * 4);
    int*   row_ptr = (int*)take((size_t)N_NODES * 4);
    int*   cnt     = (int*)take((size_t)N_NODES * 4);
    float* inv     = (float*)take((size_t)N_NODES * 4);
    u16*   xh      = (u16*)take((size_t)N_NODES * D * 2);
    u16*   h0h     = (u16*)take((size_t)N_NODES * D * 2);
    u16*   h1h     = (u16*)take((size_t)N_NODES * D * 2);

    const int BLK = 256;
    const int conv_grid  = (N_NODES * D / 4 + BLK - 1) / BLK;
    const int layer_grid = (N_NODES + 63) / 64;    // 64 nodes per block

    // ---- deterministic bucketed partition + CSR (zero global atomics) ----
    hist_kernel<<<NCHUNK, PBLK, 0, stream>>>(dst, hist);
    cscan_kernel<<<1, 1024, 0, stream>>>(hist, bptr);
    part_kernel<<<NCHUNK, PBLK, 0, stream>>>(src, dst, hist, pairs);
    local_csr_kernel<<<NBUCKETS, BLK, 0, stream>>>(pairs, bptr, row_ptr, cnt, inv, csr_src);
    tof16_kernel<<<conv_grid, BLK, 0, stream>>>(x, xh, N_NODES * D / 4);

    // ---- 3 fused layers (intermediates are f16-only) ----
    sage_layer<<<layer_grid, BLK, 0, stream>>>(xh,  row_ptr, cnt, csr_src, inv, Wl0, Wr0, b0, nullptr, h0h, 1);
    sage_layer<<<layer_grid, BLK, 0, stream>>>(h0h, row_ptr, cnt, csr_src, inv, Wl1, Wr1, b1, nullptr, h1h, 1);
    sage_layer<<<layer_grid, BLK, 0, stream>>>(h1h, row_ptr, cnt, csr_src, inv, Wl2, Wr2, b2, out, nullptr, 0);
}

// Round 8
// 216.694 us; speedup vs baseline: 11.3246x; 1.4168x over previous
//
#include <hip/hip_runtime.h>

#define N_NODES 100000
#define N_EDGES 1600000
#define D 64
#define NB 131                 // nodes per bucket
#define NBUCKETS 764           // ceil(100000/131)
#define PCHUNK 8192            // edges per partition chunk
#define NCHUNK 196             // ceil(N_EDGES / PCHUNK)
#define PBLK 1024

typedef unsigned int u32;
typedef unsigned short u16;
typedef _Float16 f16;
typedef f16 f16x8 __attribute__((ext_vector_type(8)));
typedef float f32x4 __attribute__((ext_vector_type(4)));

// ---------------- pass 1: per-chunk bucket histogram (LDS atomics only) ----------------
__global__ __launch_bounds__(PBLK) void hist_kernel(const int* __restrict__ dst,
                                                    int* __restrict__ hist) {
    __shared__ int hcnt[NBUCKETS];
    int t = threadIdx.x;
    int c0 = blockIdx.x * PCHUNK;
    int nloc = min(PCHUNK, N_EDGES - c0);
    for (int i = t; i < NBUCKETS; i += PBLK) hcnt[i] = 0;
    __syncthreads();
    for (int i = t; i < nloc; i += PBLK) atomicAdd(&hcnt[dst[c0 + i] / NB], 1);
    __syncthreads();
    for (int i = t; i < NBUCKETS; i += PBLK) hist[blockIdx.x * NBUCKETS + i] = hcnt[i];
}

// ---------------- pass 2: column sums -> bptr; rewrite hist as chunk base offsets ----------------
__global__ __launch_bounds__(1024) void cscan_kernel(int* __restrict__ hist,
                                                     int* __restrict__ bptr) {
    __shared__ int s[1024];
    int t = threadIdx.x;
    int tot = 0;
    if (t < NBUCKETS)
        for (int c = 0; c < NCHUNK; ++c) tot += hist[c * NBUCKETS + t];
    s[t] = tot;
    __syncthreads();
    for (int off = 1; off < 1024; off <<= 1) {
        int a = (t >= off) ? s[t - off] : 0;
        __syncthreads();
        s[t] += a;
        __syncthreads();
    }
    if (t < NBUCKETS) {
        int run = s[t] - tot;          // exclusive prefix over buckets
        bptr[t] = run;
        for (int c = 0; c < NCHUNK; ++c) {
            int v = hist[c * NBUCKETS + t];
            hist[c * NBUCKETS + t] = run;
            run += v;
        }
    }
    if (t == NBUCKETS - 1) bptr[NBUCKETS] = s[t];
}

// ---------------- pass 3: partition (zero global atomics) ----------------
__global__ __launch_bounds__(PBLK) void part_kernel(const int* __restrict__ src,
                                                    const int* __restrict__ dst,
                                                    const int* __restrict__ cbase,
                                                    u32* __restrict__ pairs) {
    __shared__ int hcur[NBUCKETS];
    __shared__ int hb[NBUCKETS];
    int t = threadIdx.x;
    int c0 = blockIdx.x * PCHUNK;
    int nloc = min(PCHUNK, N_EDGES - c0);
    for (int i = t; i < NBUCKETS; i += PBLK) {
        hcur[i] = 0;
        hb[i] = cbase[blockIdx.x * NBUCKETS + i];
    }
    __syncthreads();
    for (int i = t; i < nloc; i += PBLK) {
        int s = src[c0 + i];
        int d = dst[c0 + i];
        int b = d / NB;
        int r = atomicAdd(&hcur[b], 1);
        pairs[hb[b] + r] = ((u32)(d - b * NB) << 24) | (u32)s;
    }
}

// ---------------- per-bucket local CSR: histogram -> scan -> fill ----------------
__global__ __launch_bounds__(256) void local_csr_kernel(
    const u32* __restrict__ pairs, const int* __restrict__ bptr,
    int* __restrict__ row_ptr, int* __restrict__ cnt, float* __restrict__ inv,
    int* __restrict__ csr_src)
{
    __shared__ int lcnt[NB];
    __shared__ int lofs[NB];
    __shared__ int s[256];

    int t = threadIdx.x, b = blockIdx.x;
    int e0 = bptr[b], e1 = bptr[b + 1];
    int nb0 = b * NB;

    for (int i = t; i < NB; i += 256) lcnt[i] = 0;
    __syncthreads();
    for (int e = e0 + t; e < e1; e += 256) atomicAdd(&lcnt[pairs[e] >> 24], 1);
    __syncthreads();

    int v = (t < NB) ? lcnt[t] : 0;
    s[t] = v;
    __syncthreads();
    for (int off = 1; off < 256; off <<= 1) {
        int a = (t >= off) ? s[t - off] : 0;
        __syncthreads();
        s[t] += a;
        __syncthreads();
    }
    if (t < NB) {
        int node = nb0 + t;
        if (node < N_NODES) {
            int excl = s[t] - v;
            lofs[t] = excl;
            row_ptr[node] = e0 + excl;
            cnt[node] = v;
            inv[node] = 1.0f / fmaxf((float)v, 1.0f);
        }
        lcnt[t] = 0;   // reuse as fill cursor
    }
    __syncthreads();
    for (int e = e0 + t; e < e1; e += 256) {
        u32 p = pairs[e];
        int dl = (int)(p >> 24);
        int pos = atomicAdd(&lcnt[dl], 1);
        csr_src[e0 + lofs[dl] + pos] = (int)(p & 0xFFFFFFu);
    }
}

// ---------------- f32 -> f16 conversion (4 elems/thread) ----------------
__global__ void tof16_kernel(const float* __restrict__ in, u16* __restrict__ outh, int n4) {
    int i = blockIdx.x * blockDim.x + threadIdx.x;
    if (i < n4) {
        float4 v = reinterpret_cast<const float4*>(in)[i];
        union { f16 h[4]; uint2 u; } cv;
        cv.h[0] = (f16)v.x; cv.h[1] = (f16)v.y; cv.h[2] = (f16)v.z; cv.h[3] = (f16)v.w;
        reinterpret_cast<uint2*>(outh)[i] = cv.u;
    }
}

// ---------------- precompute MFMA B-fragments for all 3 layers (R5-verified) ----------------
// Bfrag[layer][f=ktg*4+nt][lane]: lane l holds col o=nt*16+(l&15), k=(ktg&1)*32+(l>>4)*8..+8
// of W = (ktg&2) ? Wr : Wl.
__global__ void prep_bfrag(const float* __restrict__ Wl0, const float* __restrict__ Wr0,
                           const float* __restrict__ Wl1, const float* __restrict__ Wr1,
                           const float* __restrict__ Wl2, const float* __restrict__ Wr2,
                           uint4* __restrict__ Bfrag) {
    int idx = blockIdx.x * blockDim.x + threadIdx.x;
    if (idx >= 3 * 16 * 64) return;
    int layer = idx >> 10, r = idx & 1023, f = r >> 6, l = r & 63;
    const float* Wl = layer == 0 ? Wl0 : layer == 1 ? Wl1 : Wl2;
    const float* Wr = layer == 0 ? Wr0 : layer == 1 ? Wr1 : Wr2;
    int ktg = f >> 2, nt = f & 3;
    const float* W = (ktg & 2) ? Wr : Wl;
    int o = nt * 16 + (l & 15);
    int k = (ktg & 1) * 32 + (l >> 4) * 8;
    const float* s = W + o * 64 + k;
    float4 v0 = *reinterpret_cast<const float4*>(s);
    float4 v1 = *reinterpret_cast<const float4*>(s + 4);
    union { f16x8 h; uint4 u; } cv;
    cv.h[0] = (f16)v0.x; cv.h[1] = (f16)v0.y; cv.h[2] = (f16)v0.z; cv.h[3] = (f16)v0.w;
    cv.h[4] = (f16)v1.x; cv.h[5] = (f16)v1.y; cv.h[6] = (f16)v1.z; cv.h[7] = (f16)v1.w;
    Bfrag[idx] = cv.u;
}

__device__ __forceinline__ void add8(float* va, uint4 r) {
    union { uint4 u; f16x8 h; } cv; cv.u = r;
    #pragma unroll
    for (int e = 0; e < 8; ++e) va[e] += (float)cv.h[e];
}

// ---------------- fused SAGE layer (MFMA, barrier-free, B from global) ----------------
// 256 threads = 4 waves; wave w owns 16 nodes. LDS = per-wave A-tile only (16.4 KB)
// -> 8 blocks/CU target occupancy (launch_bounds(256,8), VGPR<=64).
__global__ __launch_bounds__(256, 8) void sage_layer(
    const u16* __restrict__ hh,        // f16 features [N][64]
    const int* __restrict__ row_ptr, const int* __restrict__ cnt,
    const int* __restrict__ csr_src, const float* __restrict__ inv,
    const uint4* __restrict__ Bfrag,   // 16 fragments x 64 lanes (this layer)
    const float* __restrict__ bvec,
    float* __restrict__ outf,          // f32 output (nullptr to skip)
    u16* __restrict__ outh,            // f16 output (nullptr to skip)
    int relu)
{
    __shared__ u16 Atile[4][16][128];      // per-wave swizzled A (no block barriers!)

    int t = threadIdx.x;
    int w    = t >> 6;
    int lane = t & 63;
    int j8   = lane & 7;    // channel octet within row / row-lane
    int sub  = lane >> 3;   // edge subgroup 0..7
    const uint4* rows = reinterpret_cast<const uint4*>(hh);   // 8 x uint4 per node

    int base = blockIdx.x * 64 + w * 16;

    float bias[4];
    #pragma unroll
    for (int nt = 0; nt < 4; ++nt) bias[nt] = bvec[nt * 16 + (lane & 15)];

    // ---- gather 16 nodes into A-tile ----
    for (int n = 0; n < 16; ++n) {
        int node = base + n;
        if (node >= N_NODES) break;             // wave-uniform
        uint4 selfrow = rows[node * 8 + j8];    // in flight during gather
        int s0 = row_ptr[node];
        int c  = cnt[node];
        float va[8] = {0.f,0.f,0.f,0.f,0.f,0.f,0.f,0.f};
        int j = 0;
        for (; j + 16 <= c; j += 16) {
            int i0 = csr_src[s0 + j + sub];
            int i1 = csr_src[s0 + j + 8 + sub];
            uint4 r0 = rows[i0 * 8 + j8];
            uint4 r1 = rows[i1 * 8 + j8];
            add8(va, r0);
            add8(va, r1);
        }
        for (; j + 8 <= c; j += 8) {
            int i0 = csr_src[s0 + j + sub];
            uint4 r0 = rows[i0 * 8 + j8];
            add8(va, r0);
        }
        int rem = c - j;
        if (sub < rem) {
            int i0 = csr_src[s0 + j + sub];
            uint4 r0 = rows[i0 * 8 + j8];
            add8(va, r0);
        }
        // butterfly reduce over the 8 edge-subgroups
        #pragma unroll
        for (int e = 0; e < 8; ++e) {
            va[e] += __shfl_xor(va[e], 8);
            va[e] += __shfl_xor(va[e], 16);
            va[e] += __shfl_xor(va[e], 32);
        }
        int chunk = j8 ^ (n & 7);
        if (lane < 8) {                 // mean -> k 0..63
            float sc = inv[node];
            union { f16x8 h; uint4 u; } cv;
            #pragma unroll
            for (int e = 0; e < 8; ++e) cv.h[e] = (f16)(va[e] * sc);
            *reinterpret_cast<uint4*>(&Atile[w][n][chunk * 8]) = cv.u;
        } else if (lane < 16) {         // self -> k 64..127
            *reinterpret_cast<uint4*>(&Atile[w][n][64 + chunk * 8]) = selfrow;
        }
    }

    // ---- fragment reads + 16 MFMAs (B straight from global, loaded at use) ----
    f32x4 acc[4] = {};
    int row = lane & 15, kg = lane >> 4;
    #pragma unroll
    for (int ktg = 0; ktg < 4; ++ktg) {
        int idx16 = ktg * 4 + kg;
        int swz = (idx16 & 8) | ((idx16 & 7) ^ (row & 7));
        uint4 a = *reinterpret_cast<const uint4*>(&Atile[w][row][swz * 8]);
        union { uint4 u; f16x8 h; } av; av.u = a;
        #pragma unroll
        for (int nt = 0; nt < 4; ++nt) {
            union { uint4 u; f16x8 h; } bv; bv.u = Bfrag[(ktg * 4 + nt) * 64 + lane];
            acc[nt] = __builtin_amdgcn_mfma_f32_16x16x32_f16(av.h, bv.h, acc[nt], 0, 0, 0);
        }
    }

    // ---- epilogue: bias (+ReLU), stores. C: col=lane&15, row=(lane>>4)*4+reg ----
    #pragma unroll
    for (int nt = 0; nt < 4; ++nt) {
        int o = nt * 16 + (lane & 15);
        #pragma unroll
        for (int r = 0; r < 4; ++r) {
            int n = kg * 4 + r;
            int node = base + n;
            if (node < N_NODES) {
                float vout = acc[nt][r] + bias[nt];
                if (relu) vout = fmaxf(vout, 0.f);
                if (outf) outf[node * 64 + o] = vout;
                if (outh) {
                    union { f16 h; u16 u; } cv; cv.h = (f16)vout;
                    outh[node * 64 + o] = cv.u;
                }
            }
        }
    }
}

extern "C" void kernel_launch(void* const* d_in, const int* in_sizes, int n_in,
                              void* d_out, int out_size, void* d_ws, size_t ws_size,
                              hipStream_t stream) {
    const float* x   = (const float*)d_in[0];
    const int*   ei  = (const int*)d_in[1];
    const int*   src = ei;
    const int*   dst = ei + N_EDGES;
    const float* Wl0 = (const float*)d_in[2];
    const float* Wr0 = (const float*)d_in[3];
    const float* b0  = (const float*)d_in[4];
    const float* Wl1 = (const float*)d_in[5];
    const float* Wr1 = (const float*)d_in[6];
    const float* b1  = (const float*)d_in[7];
    const float* Wl2 = (const float*)d_in[8];
    const float* Wr2 = (const float*)d_in[9];
    const float* b2  = (const float*)d_in[10];
    float* out = (float*)d_out;

    // ---- workspace layout (256B-aligned regions) ----
    char* p = (char*)d_ws;
    auto take = [&](size_t bytes) { char* r = p; p += (bytes + 255) & ~(size_t)255; return r; };
    int*   hist    = (int*)take((size_t)NCHUNK * NBUCKETS * 4);
    int*   bptr    = (int*)take((size_t)(NBUCKETS + 1) * 4);
    u32*   pairs   = (u32*)take((size_t)N_EDGES * 4);
    int*   csr_src = (int*)take((size_t)N_EDGES * 4);
    int*   row_ptr = (int*)take((size_t)N_NODES * 4);
    int*   cnt     = (int*)take((size_t)N_NODES * 4);
    float* inv     = (float*)take((size_t)N_NODES * 4);
    uint4* Bfrag   = (uint4*)take((size_t)3 * 16 * 64 * 16);
    u16*   xh      = (u16*)take((size_t)N_NODES * D * 2);
    u16*   h0h     = (u16*)take((size_t)N_NODES * D * 2);
    u16*   h1h     = (u16*)take((size_t)N_NODES * D * 2);

    const int BLK = 256;
    const int conv_grid  = (N_NODES * D / 4 + BLK - 1) / BLK;
    const int layer_grid = (N_NODES + 63) / 64;    // 64 nodes per block

    // ---- deterministic bucketed partition + CSR (zero global atomics) ----
    hist_kernel<<<NCHUNK, PBLK, 0, stream>>>(dst, hist);
    cscan_kernel<<<1, 1024, 0, stream>>>(hist, bptr);
    part_kernel<<<NCHUNK, PBLK, 0, stream>>>(src, dst, hist, pairs);
    local_csr_kernel<<<NBUCKETS, BLK, 0, stream>>>(pairs, bptr, row_ptr, cnt, inv, csr_src);
    tof16_kernel<<<conv_grid, BLK, 0, stream>>>(x, xh, N_NODES * D / 4);
    prep_bfrag<<<(3 * 1024 + BLK - 1) / BLK, BLK, 0, stream>>>(Wl0, Wr0, Wl1, Wr1, Wl2, Wr2, Bfrag);

    // ---- 3 fused layers (intermediates are f16-only) ----
    sage_layer<<<layer_grid, BLK, 0, stream>>>(xh,  row_ptr, cnt, csr_src, inv, Bfrag,        b0, nullptr, h0h, 1);
    sage_layer<<<layer_grid, BLK, 0, stream>>>(h0h, row_ptr, cnt, csr_src, inv, Bfrag + 1024, b1, nullptr, h1h, 1);
    sage_layer<<<layer_grid, BLK, 0, stream>>>(h1h, row_ptr, cnt, csr_src, inv, Bfrag + 2048, b2, out, nullptr, 0);
}

// Round 9
// 183.416 us; speedup vs baseline: 13.3793x; 1.1814x over previous
//
#include <hip/hip_runtime.h>

#define N_NODES 100000
#define N_EDGES 1600000
#define D 64
#define NB 131                 // nodes per bucket
#define NBUCKETS 764           // ceil(100000/131)
#define PCHUNK 32768           // edges per partition chunk
#define NCHUNK 49              // ceil(N_EDGES / PCHUNK)
#define PBLK 1024

typedef unsigned int u32;
typedef unsigned short u16;
typedef _Float16 f16;
typedef f16 f16x8 __attribute__((ext_vector_type(8)));
typedef float f32x4 __attribute__((ext_vector_type(4)));

// ---------------- pass 1: per-chunk bucket histogram (LDS atomics only) ----------------
__global__ __launch_bounds__(PBLK) void hist_kernel(const int* __restrict__ dst,
                                                    int* __restrict__ hist) {
    __shared__ int hcnt[NBUCKETS];
    int t = threadIdx.x;
    int c0 = blockIdx.x * PCHUNK;
    int nloc = min(PCHUNK, N_EDGES - c0);
    for (int i = t; i < NBUCKETS; i += PBLK) hcnt[i] = 0;
    __syncthreads();
    for (int i = t; i < nloc; i += PBLK) atomicAdd(&hcnt[dst[c0 + i] / NB], 1);
    __syncthreads();
    for (int i = t; i < NBUCKETS; i += PBLK) hist[blockIdx.x * NBUCKETS + i] = hcnt[i];
}

// ---------------- pass 2: column sums -> bptr; rewrite hist as chunk base offsets ----------------
__global__ __launch_bounds__(1024) void cscan_kernel(int* __restrict__ hist,
                                                     int* __restrict__ bptr) {
    __shared__ int s[1024];
    int t = threadIdx.x;
    int tot = 0;
    if (t < NBUCKETS)
        for (int c = 0; c < NCHUNK; ++c) tot += hist[c * NBUCKETS + t];
    s[t] = tot;
    __syncthreads();
    for (int off = 1; off < 1024; off <<= 1) {
        int a = (t >= off) ? s[t - off] : 0;
        __syncthreads();
        s[t] += a;
        __syncthreads();
    }
    if (t < NBUCKETS) {
        int run = s[t] - tot;          // exclusive prefix over buckets
        bptr[t] = run;
        for (int c = 0; c < NCHUNK; ++c) {
            int v = hist[c * NBUCKETS + t];
            hist[c * NBUCKETS + t] = run;
            run += v;
        }
    }
    if (t == NBUCKETS - 1) bptr[NBUCKETS] = s[t];
}

// ---------------- pass 3: partition (zero global atomics) ----------------
__global__ __launch_bounds__(PBLK) void part_kernel(const int* __restrict__ src,
                                                    const int* __restrict__ dst,
                                                    const int* __restrict__ cbase,
                                                    u32* __restrict__ pairs) {
    __shared__ int hcur[NBUCKETS];
    __shared__ int hb[NBUCKETS];
    int t = threadIdx.x;
    int c0 = blockIdx.x * PCHUNK;
    int nloc = min(PCHUNK, N_EDGES - c0);
    for (int i = t; i < NBUCKETS; i += PBLK) {
        hcur[i] = 0;
        hb[i] = cbase[blockIdx.x * NBUCKETS + i];
    }
    __syncthreads();
    for (int i = t; i < nloc; i += PBLK) {
        int s = src[c0 + i];
        int d = dst[c0 + i];
        int b = d / NB;
        int r = atomicAdd(&hcur[b], 1);
        pairs[hb[b] + r] = ((u32)(d - b * NB) << 24) | (u32)s;
    }
}

// ---------------- per-bucket local CSR: histogram -> scan -> fill ----------------
__global__ __launch_bounds__(256) void local_csr_kernel(
    const u32* __restrict__ pairs, const int* __restrict__ bptr,
    int* __restrict__ row_ptr, int* __restrict__ cnt, float* __restrict__ inv,
    int* __restrict__ csr_src)
{
    __shared__ int lcnt[NB];
    __shared__ int lofs[NB];
    __shared__ int s[256];

    int t = threadIdx.x, b = blockIdx.x;
    int e0 = bptr[b], e1 = bptr[b + 1];
    int nb0 = b * NB;

    for (int i = t; i < NB; i += 256) lcnt[i] = 0;
    __syncthreads();
    for (int e = e0 + t; e < e1; e += 256) atomicAdd(&lcnt[pairs[e] >> 24], 1);
    __syncthreads();

    int v = (t < NB) ? lcnt[t] : 0;
    s[t] = v;
    __syncthreads();
    for (int off = 1; off < 256; off <<= 1) {
        int a = (t >= off) ? s[t - off] : 0;
        __syncthreads();
        s[t] += a;
        __syncthreads();
    }
    if (t < NB) {
        int node = nb0 + t;
        if (node < N_NODES) {
            int excl = s[t] - v;
            lofs[t] = excl;
            row_ptr[node] = e0 + excl;
            cnt[node] = v;
            inv[node] = 1.0f / fmaxf((float)v, 1.0f);
        }
        lcnt[t] = 0;   // reuse as fill cursor
    }
    __syncthreads();
    for (int e = e0 + t; e < e1; e += 256) {
        u32 p = pairs[e];
        int dl = (int)(p >> 24);
        int pos = atomicAdd(&lcnt[dl], 1);
        csr_src[e0 + lofs[dl] + pos] = (int)(p & 0xFFFFFFu);
    }
}

// ---------------- f32 -> f16 conversion (4 elems/thread) ----------------
__global__ void tof16_kernel(const float* __restrict__ in, u16* __restrict__ outh, int n4) {
    int i = blockIdx.x * blockDim.x + threadIdx.x;
    if (i < n4) {
        float4 v = reinterpret_cast<const float4*>(in)[i];
        union { f16 h[4]; uint2 u; } cv;
        cv.h[0] = (f16)v.x; cv.h[1] = (f16)v.y; cv.h[2] = (f16)v.z; cv.h[3] = (f16)v.w;
        reinterpret_cast<uint2*>(outh)[i] = cv.u;
    }
}

// ---------------- precompute MFMA B-fragments for all 3 layers (verified layout) -----------
__global__ void prep_bfrag(const float* __restrict__ Wl0, const float* __restrict__ Wr0,
                           const float* __restrict__ Wl1, const float* __restrict__ Wr1,
                           const float* __restrict__ Wl2, const float* __restrict__ Wr2,
                           uint4* __restrict__ Bfrag) {
    int idx = blockIdx.x * blockDim.x + threadIdx.x;
    if (idx >= 3 * 16 * 64) return;
    int layer = idx >> 10, r = idx & 1023, f = r >> 6, l = r & 63;
    const float* Wl = layer == 0 ? Wl0 : layer == 1 ? Wl1 : Wl2;
    const float* Wr = layer == 0 ? Wr0 : layer == 1 ? Wr1 : Wr2;
    int ktg = f >> 2, nt = f & 3;
    const float* W = (ktg & 2) ? Wr : Wl;
    int o = nt * 16 + (l & 15);
    int k = (ktg & 1) * 32 + (l >> 4) * 8;
    const float* s = W + o * 64 + k;
    float4 v0 = *reinterpret_cast<const float4*>(s);
    float4 v1 = *reinterpret_cast<const float4*>(s + 4);
    union { f16x8 h; uint4 u; } cv;
    cv.h[0] = (f16)v0.x; cv.h[1] = (f16)v0.y; cv.h[2] = (f16)v0.z; cv.h[3] = (f16)v0.w;
    cv.h[4] = (f16)v1.x; cv.h[5] = (f16)v1.y; cv.h[6] = (f16)v1.z; cv.h[7] = (f16)v1.w;
    Bfrag[idx] = cv.u;
}

__device__ __forceinline__ void add8(float* va, uint4 r) {
    union { uint4 u; f16x8 h; } cv; cv.u = r;
    #pragma unroll
    for (int e = 0; e < 8; ++e) va[e] += (float)cv.h[e];
}

// ---------------- fused SAGE layer (MFMA, barrier-free, butterfly-free gather) -------------
// 256 threads = 4 waves; wave w owns 16 nodes. Each 8-lane subgroup (sg) owns its own
// node per slot (2 slots x 8 sgs = 16 nodes): serial edge loop, unroll 4 -> 32 rows in
// flight per wave, ZERO shuffle ops. Subgroup writes its mean/self row directly into the
// verified Atile slot (chunk = j8 ^ (n&7)); MFMA + epilogue identical to R8.
__global__ __launch_bounds__(256, 8) void sage_layer(
    const u16* __restrict__ hh,        // f16 features [N][64]
    const int* __restrict__ row_ptr, const int* __restrict__ cnt,
    const int* __restrict__ csr_src, const float* __restrict__ inv,
    const uint4* __restrict__ Bfrag,   // 16 fragments x 64 lanes (this layer)
    const float* __restrict__ bvec,
    float* __restrict__ outf,          // f32 output (nullptr to skip)
    u16* __restrict__ outh,            // f16 output (nullptr to skip)
    int relu)
{
    __shared__ u16 Atile[4][16][128];      // per-wave swizzled A (no block barriers)

    int t = threadIdx.x;
    int w    = t >> 6;
    int lane = t & 63;
    int j8   = lane & 7;    // channel octet within row
    int sg   = lane >> 3;   // node slot within group of 8
    const uint4* rows = reinterpret_cast<const uint4*>(hh);   // 8 x uint4 per node

    int base = blockIdx.x * 64 + w * 16;

    float bias[4];
    #pragma unroll
    for (int nt = 0; nt < 4; ++nt) bias[nt] = bvec[nt * 16 + (lane & 15)];

    // ---- gather: each subgroup accumulates its own node (2 slots) ----
    #pragma unroll
    for (int slot = 0; slot < 2; ++slot) {
        int n = slot * 8 + sg;              // 0..15
        int node = base + n;
        bool valid = node < N_NODES;
        int nodec = valid ? node : N_NODES - 1;
        uint4 selfrow = rows[nodec * 8 + j8];       // in flight during gather
        int s0 = row_ptr[nodec];
        int c  = valid ? cnt[nodec] : 0;
        float va[8] = {0.f,0.f,0.f,0.f,0.f,0.f,0.f,0.f};
        int j = 0;
        for (; j + 4 <= c; j += 4) {
            int i0 = csr_src[s0 + j];
            int i1 = csr_src[s0 + j + 1];
            int i2 = csr_src[s0 + j + 2];
            int i3 = csr_src[s0 + j + 3];
            uint4 r0 = rows[i0 * 8 + j8];
            uint4 r1 = rows[i1 * 8 + j8];
            uint4 r2 = rows[i2 * 8 + j8];
            uint4 r3 = rows[i3 * 8 + j8];
            add8(va, r0); add8(va, r1); add8(va, r2); add8(va, r3);
        }
        for (; j < c; ++j) {
            int i0 = csr_src[s0 + j];
            add8(va, rows[i0 * 8 + j8]);
        }
        float sc = inv[nodec];
        union { f16x8 h; uint4 u; } mv;
        #pragma unroll
        for (int e = 0; e < 8; ++e) mv.h[e] = (f16)(va[e] * sc);
        int chunk = j8 ^ (n & 7);
        if (valid) {
            *reinterpret_cast<uint4*>(&Atile[w][n][chunk * 8]) = mv.u;       // mean, k 0..63
            *reinterpret_cast<uint4*>(&Atile[w][n][64 + chunk * 8]) = selfrow; // self, k 64..127
        }
    }

    // ---- fragment reads + 16 MFMAs (B straight from global) ----
    f32x4 acc[4] = {};
    int row = lane & 15, kg = lane >> 4;
    #pragma unroll
    for (int ktg = 0; ktg < 4; ++ktg) {
        int idx16 = ktg * 4 + kg;
        int swz = (idx16 & 8) | ((idx16 & 7) ^ (row & 7));
        uint4 a = *reinterpret_cast<const uint4*>(&Atile[w][row][swz * 8]);
        union { uint4 u; f16x8 h; } av; av.u = a;
        #pragma unroll
        for (int nt = 0; nt < 4; ++nt) {
            union { uint4 u; f16x8 h; } bv; bv.u = Bfrag[(ktg * 4 + nt) * 64 + lane];
            acc[nt] = __builtin_amdgcn_mfma_f32_16x16x32_f16(av.h, bv.h, acc[nt], 0, 0, 0);
        }
    }

    // ---- epilogue: bias (+ReLU), stores. C: col=lane&15, row=(lane>>4)*4+reg ----
    #pragma unroll
    for (int nt = 0; nt < 4; ++nt) {
        int o = nt * 16 + (lane & 15);
        #pragma unroll
        for (int r = 0; r < 4; ++r) {
            int n = kg * 4 + r;
            int node = base + n;
            if (node < N_NODES) {
                float vout = acc[nt][r] + bias[nt];
                if (relu) vout = fmaxf(vout, 0.f);
                if (outf) outf[node * 64 + o] = vout;
                if (outh) {
                    union { f16 h; u16 u; } cv; cv.h = (f16)vout;
                    outh[node * 64 + o] = cv.u;
                }
            }
        }
    }
}

extern "C" void kernel_launch(void* const* d_in, const int* in_sizes, int n_in,
                              void* d_out, int out_size, void* d_ws, size_t ws_size,
                              hipStream_t stream) {
    const float* x   = (const float*)d_in[0];
    const int*   ei  = (const int*)d_in[1];
    const int*   src = ei;
    const int*   dst = ei + N_EDGES;
    const float* Wl0 = (const float*)d_in[2];
    const float* Wr0 = (const float*)d_in[3];
    const float* b0  = (const float*)d_in[4];
    const float* Wl1 = (const float*)d_in[5];
    const float* Wr1 = (const float*)d_in[6];
    const float* b1  = (const float*)d_in[7];
    const float* Wl2 = (const float*)d_in[8];
    const float* Wr2 = (const float*)d_in[9];
    const float* b2  = (const float*)d_in[10];
    float* out = (float*)d_out;

    // ---- workspace layout (256B-aligned regions) ----
    char* p = (char*)d_ws;
    auto take = [&](size_t bytes) { char* r = p; p += (bytes + 255) & ~(size_t)255; return r; };
    int*   hist    = (int*)take((size_t)NCHUNK * NBUCKETS * 4);
    int*   bptr    = (int*)take((size_t)(NBUCKETS + 1) * 4);
    u32*   pairs   = (u32*)take((size_t)N_EDGES * 4);
    int*   csr_src = (int*)take((size_t)N_EDGES * 4);
    int*   row_ptr = (int*)take((size_t)N_NODES * 4);
    int*   cnt     = (int*)take((size_t)N_NODES * 4);
    float* inv     = (float*)take((size_t)N_NODES * 4);
    uint4* Bfrag   = (uint4*)take((size_t)3 * 16 * 64 * 16);
    u16*   xh      = (u16*)take((size_t)N_NODES * D * 2);
    u16*   h0h     = (u16*)take((size_t)N_NODES * D * 2);
    u16*   h1h     = (u16*)take((size_t)N_NODES * D * 2);

    const int BLK = 256;
    const int conv_grid  = (N_NODES * D / 4 + BLK - 1) / BLK;
    const int layer_grid = (N_NODES + 63) / 64;    // 64 nodes per block

    // ---- deterministic bucketed partition + CSR (zero global atomics) ----
    hist_kernel<<<NCHUNK, PBLK, 0, stream>>>(dst, hist);
    cscan_kernel<<<1, 1024, 0, stream>>>(hist, bptr);
    part_kernel<<<NCHUNK, PBLK, 0, stream>>>(src, dst, hist, pairs);
    local_csr_kernel<<<NBUCKETS, BLK, 0, stream>>>(pairs, bptr, row_ptr, cnt, inv, csr_src);
    tof16_kernel<<<conv_grid, BLK, 0, stream>>>(x, xh, N_NODES * D / 4);
    prep_bfrag<<<(3 * 1024 + BLK - 1) / BLK, BLK, 0, stream>>>(Wl0, Wr0, Wl1, Wr1, Wl2, Wr2, Bfrag);

    // ---- 3 fused layers (intermediates are f16-only) ----
    sage_layer<<<layer_grid, BLK, 0, stream>>>(xh,  row_ptr, cnt, csr_src, inv, Bfrag,        b0, nullptr, h0h, 1);
    sage_layer<<<layer_grid, BLK, 0, stream>>>(h0h, row_ptr, cnt, csr_src, inv, Bfrag + 1024, b1, nullptr, h1h, 1);
    sage_layer<<<layer_grid, BLK, 0, stream>>>(h1h, row_ptr, cnt, csr_src, inv, Bfrag + 2048, b2, out, nullptr, 0);
}

// Round 10
// 182.761 us; speedup vs baseline: 13.4272x; 1.0036x over previous
//
#include <hip/hip_runtime.h>

#define N_NODES 100000
#define N_EDGES 1600000
#define D 64
#define NB 131                 // nodes per bucket
#define NBUCKETS 764           // ceil(100000/131)
#define PCHUNK 8192            // edges per partition chunk (196 blocks: parallelism > coalescing)
#define NCHUNK 196             // ceil(N_EDGES / PCHUNK)
#define PBLK 1024

typedef unsigned int u32;
typedef unsigned short u16;
typedef _Float16 f16;
typedef f16 f16x8 __attribute__((ext_vector_type(8)));
typedef float f32x4 __attribute__((ext_vector_type(4)));

// ---------------- pass 1: per-chunk bucket histogram (LDS atomics only) ----------------
__global__ __launch_bounds__(PBLK) void hist_kernel(const int* __restrict__ dst,
                                                    int* __restrict__ hist) {
    __shared__ int hcnt[NBUCKETS];
    int t = threadIdx.x;
    int c0 = blockIdx.x * PCHUNK;
    int nloc = min(PCHUNK, N_EDGES - c0);
    for (int i = t; i < NBUCKETS; i += PBLK) hcnt[i] = 0;
    __syncthreads();
    for (int i = t; i < nloc; i += PBLK) atomicAdd(&hcnt[dst[c0 + i] / NB], 1);
    __syncthreads();
    for (int i = t; i < NBUCKETS; i += PBLK) hist[blockIdx.x * NBUCKETS + i] = hcnt[i];
}

// ---------------- pass 2: column sums -> bptr; rewrite hist as chunk base offsets ----------------
__global__ __launch_bounds__(1024) void cscan_kernel(int* __restrict__ hist,
                                                     int* __restrict__ bptr) {
    __shared__ int s[1024];
    int t = threadIdx.x;
    int tot = 0;
    if (t < NBUCKETS)
        for (int c = 0; c < NCHUNK; ++c) tot += hist[c * NBUCKETS + t];
    s[t] = tot;
    __syncthreads();
    for (int off = 1; off < 1024; off <<= 1) {
        int a = (t >= off) ? s[t - off] : 0;
        __syncthreads();
        s[t] += a;
        __syncthreads();
    }
    if (t < NBUCKETS) {
        int run = s[t] - tot;          // exclusive prefix over buckets
        bptr[t] = run;
        for (int c = 0; c < NCHUNK; ++c) {
            int v = hist[c * NBUCKETS + t];
            hist[c * NBUCKETS + t] = run;
            run += v;
        }
    }
    if (t == NBUCKETS - 1) bptr[NBUCKETS] = s[t];
}

// ---------------- pass 3: partition (zero global atomics) ----------------
__global__ __launch_bounds__(PBLK) void part_kernel(const int* __restrict__ src,
                                                    const int* __restrict__ dst,
                                                    const int* __restrict__ cbase,
                                                    u32* __restrict__ pairs) {
    __shared__ int hcur[NBUCKETS];
    __shared__ int hb[NBUCKETS];
    int t = threadIdx.x;
    int c0 = blockIdx.x * PCHUNK;
    int nloc = min(PCHUNK, N_EDGES - c0);
    for (int i = t; i < NBUCKETS; i += PBLK) {
        hcur[i] = 0;
        hb[i] = cbase[blockIdx.x * NBUCKETS + i];
    }
    __syncthreads();
    for (int i = t; i < nloc; i += PBLK) {
        int s = src[c0 + i];
        int d = dst[c0 + i];
        int b = d / NB;
        int r = atomicAdd(&hcur[b], 1);
        pairs[hb[b] + r] = ((u32)(d - b * NB) << 24) | (u32)s;
    }
}

// ---------------- per-bucket local CSR: histogram -> scan -> fill ----------------
__global__ __launch_bounds__(256) void local_csr_kernel(
    const u32* __restrict__ pairs, const int* __restrict__ bptr,
    int* __restrict__ row_ptr, int* __restrict__ cnt, float* __restrict__ inv,
    int* __restrict__ csr_src)
{
    __shared__ int lcnt[NB];
    __shared__ int lofs[NB];
    __shared__ int s[256];

    int t = threadIdx.x, b = blockIdx.x;
    int e0 = bptr[b], e1 = bptr[b + 1];
    int nb0 = b * NB;

    for (int i = t; i < NB; i += 256) lcnt[i] = 0;
    __syncthreads();
    for (int e = e0 + t; e < e1; e += 256) atomicAdd(&lcnt[pairs[e] >> 24], 1);
    __syncthreads();

    int v = (t < NB) ? lcnt[t] : 0;
    s[t] = v;
    __syncthreads();
    for (int off = 1; off < 256; off <<= 1) {
        int a = (t >= off) ? s[t - off] : 0;
        __syncthreads();
        s[t] += a;
        __syncthreads();
    }
    if (t < NB) {
        int node = nb0 + t;
        if (node < N_NODES) {
            int excl = s[t] - v;
            lofs[t] = excl;
            row_ptr[node] = e0 + excl;
            cnt[node] = v;
            inv[node] = 1.0f / fmaxf((float)v, 1.0f);
        }
        lcnt[t] = 0;   // reuse as fill cursor
    }
    __syncthreads();
    for (int e = e0 + t; e < e1; e += 256) {
        u32 p = pairs[e];
        int dl = (int)(p >> 24);
        int pos = atomicAdd(&lcnt[dl], 1);
        csr_src[e0 + lofs[dl] + pos] = (int)(p & 0xFFFFFFu);
    }
}

// ---------------- f32 -> f16 conversion (4 elems/thread) ----------------
__global__ void tof16_kernel(const float* __restrict__ in, u16* __restrict__ outh, int n4) {
    int i = blockIdx.x * blockDim.x + threadIdx.x;
    if (i < n4) {
        float4 v = reinterpret_cast<const float4*>(in)[i];
        union { f16 h[4]; uint2 u; } cv;
        cv.h[0] = (f16)v.x; cv.h[1] = (f16)v.y; cv.h[2] = (f16)v.z; cv.h[3] = (f16)v.w;
        reinterpret_cast<uint2*>(outh)[i] = cv.u;
    }
}

// ---------------- precompute MFMA B-fragments for all 3 layers (verified layout) -----------
__global__ void prep_bfrag(const float* __restrict__ Wl0, const float* __restrict__ Wr0,
                           const float* __restrict__ Wl1, const float* __restrict__ Wr1,
                           const float* __restrict__ Wl2, const float* __restrict__ Wr2,
                           uint4* __restrict__ Bfrag) {
    int idx = blockIdx.x * blockDim.x + threadIdx.x;
    if (idx >= 3 * 16 * 64) return;
    int layer = idx >> 10, r = idx & 1023, f = r >> 6, l = r & 63;
    const float* Wl = layer == 0 ? Wl0 : layer == 1 ? Wl1 : Wl2;
    const float* Wr = layer == 0 ? Wr0 : layer == 1 ? Wr1 : Wr2;
    int ktg = f >> 2, nt = f & 3;
    const float* W = (ktg & 2) ? Wr : Wl;
    int o = nt * 16 + (l & 15);
    int k = (ktg & 1) * 32 + (l >> 4) * 8;
    const float* s = W + o * 64 + k;
    float4 v0 = *reinterpret_cast<const float4*>(s);
    float4 v1 = *reinterpret_cast<const float4*>(s + 4);
    union { f16x8 h; uint4 u; } cv;
    cv.h[0] = (f16)v0.x; cv.h[1] = (f16)v0.y; cv.h[2] = (f16)v0.z; cv.h[3] = (f16)v0.w;
    cv.h[4] = (f16)v1.x; cv.h[5] = (f16)v1.y; cv.h[6] = (f16)v1.z; cv.h[7] = (f16)v1.w;
    Bfrag[idx] = cv.u;
}

__device__ __forceinline__ void add8(float* va, uint4 r) {
    union { uint4 u; f16x8 h; } cv; cv.u = r;
    #pragma unroll
    for (int e = 0; e < 8; ++e) va[e] += (float)cv.h[e];
}

// ---------------- fused SAGE layer (MFMA, barrier-free, butterfly-free gather) -------------
// 256 threads = 4 waves; wave w owns 16 nodes. Each 8-lane subgroup owns its own node
// per slot (2 slots x 8 sgs = 16 nodes): serial edge loop with next-quad index
// prefetch (index-load latency hides under the add chain), zero shuffle ops.
__global__ __launch_bounds__(256, 8) void sage_layer(
    const u16* __restrict__ hh,        // f16 features [N][64]
    const int* __restrict__ row_ptr, const int* __restrict__ cnt,
    const int* __restrict__ csr_src, const float* __restrict__ inv,
    const uint4* __restrict__ Bfrag,   // 16 fragments x 64 lanes (this layer)
    const float* __restrict__ bvec,
    float* __restrict__ outf,          // f32 output (nullptr to skip)
    u16* __restrict__ outh,            // f16 output (nullptr to skip)
    int relu)
{
    __shared__ u16 Atile[4][16][128];      // per-wave swizzled A (no block barriers)

    int t = threadIdx.x;
    int w    = t >> 6;
    int lane = t & 63;
    int j8   = lane & 7;    // channel octet within row
    int sg   = lane >> 3;   // node slot within group of 8
    const uint4* rows = reinterpret_cast<const uint4*>(hh);   // 8 x uint4 per node

    int base = blockIdx.x * 64 + w * 16;

    float bias[4];
    #pragma unroll
    for (int nt = 0; nt < 4; ++nt) bias[nt] = bvec[nt * 16 + (lane & 15)];

    // ---- gather: each subgroup accumulates its own node (2 slots) ----
    #pragma unroll
    for (int slot = 0; slot < 2; ++slot) {
        int n = slot * 8 + sg;              // 0..15
        int node = base + n;
        bool valid = node < N_NODES;
        int nodec = valid ? node : N_NODES - 1;
        uint4 selfrow = rows[nodec * 8 + j8];       // in flight during gather
        int s0 = row_ptr[nodec];
        int c  = valid ? cnt[nodec] : 0;
        float va[8] = {0.f,0.f,0.f,0.f,0.f,0.f,0.f,0.f};
        int j = 0;
        int i0 = 0, i1 = 0, i2 = 0, i3 = 0;
        bool have = (c >= 4);
        if (have) {
            i0 = csr_src[s0];     i1 = csr_src[s0 + 1];
            i2 = csr_src[s0 + 2]; i3 = csr_src[s0 + 3];
        }
        while (have) {
            uint4 r0 = rows[i0 * 8 + j8];
            uint4 r1 = rows[i1 * 8 + j8];
            uint4 r2 = rows[i2 * 8 + j8];
            uint4 r3 = rows[i3 * 8 + j8];
            j += 4;
            have = (j + 4 <= c);
            if (have) {           // prefetch next quad's indices before the add chain
                i0 = csr_src[s0 + j];     i1 = csr_src[s0 + j + 1];
                i2 = csr_src[s0 + j + 2]; i3 = csr_src[s0 + j + 3];
            }
            add8(va, r0); add8(va, r1); add8(va, r2); add8(va, r3);
        }
        for (; j < c; ++j) {
            add8(va, rows[csr_src[s0 + j] * 8 + j8]);
        }
        float sc = inv[nodec];
        union { f16x8 h; uint4 u; } mv;
        #pragma unroll
        for (int e = 0; e < 8; ++e) mv.h[e] = (f16)(va[e] * sc);
        int chunk = j8 ^ (n & 7);
        if (valid) {
            *reinterpret_cast<uint4*>(&Atile[w][n][chunk * 8]) = mv.u;         // mean, k 0..63
            *reinterpret_cast<uint4*>(&Atile[w][n][64 + chunk * 8]) = selfrow; // self, k 64..127
        }
    }

    // ---- fragment reads + 16 MFMAs (B straight from global) ----
    f32x4 acc[4] = {};
    int row = lane & 15, kg = lane >> 4;
    #pragma unroll
    for (int ktg = 0; ktg < 4; ++ktg) {
        int idx16 = ktg * 4 + kg;
        int swz = (idx16 & 8) | ((idx16 & 7) ^ (row & 7));
        uint4 a = *reinterpret_cast<const uint4*>(&Atile[w][row][swz * 8]);
        union { uint4 u; f16x8 h; } av; av.u = a;
        #pragma unroll
        for (int nt = 0; nt < 4; ++nt) {
            union { uint4 u; f16x8 h; } bv; bv.u = Bfrag[(ktg * 4 + nt) * 64 + lane];
            acc[nt] = __builtin_amdgcn_mfma_f32_16x16x32_f16(av.h, bv.h, acc[nt], 0, 0, 0);
        }
    }

    // ---- epilogue: bias (+ReLU), stores. C: col=lane&15, row=(lane>>4)*4+reg ----
    #pragma unroll
    for (int nt = 0; nt < 4; ++nt) {
        int o = nt * 16 + (lane & 15);
        #pragma unroll
        for (int r = 0; r < 4; ++r) {
            int n = kg * 4 + r;
            int node = base + n;
            if (node < N_NODES) {
                float vout = acc[nt][r] + bias[nt];
                if (relu) vout = fmaxf(vout, 0.f);
                if (outf) outf[node * 64 + o] = vout;
                if (outh) {
                    union { f16 h; u16 u; } cv; cv.h = (f16)vout;
                    outh[node * 64 + o] = cv.u;
                }
            }
        }
    }
}

extern "C" void kernel_launch(void* const* d_in, const int* in_sizes, int n_in,
                              void* d_out, int out_size, void* d_ws, size_t ws_size,
                              hipStream_t stream) {
    const float* x   = (const float*)d_in[0];
    const int*   ei  = (const int*)d_in[1];
    const int*   src = ei;
    const int*   dst = ei + N_EDGES;
    const float* Wl0 = (const float*)d_in[2];
    const float* Wr0 = (const float*)d_in[3];
    const float* b0  = (const float*)d_in[4];
    const float* Wl1 = (const float*)d_in[5];
    const float* Wr1 = (const float*)d_in[6];
    const float* b1  = (const float*)d_in[7];
    const float* Wl2 = (const float*)d_in[8];
    const float* Wr2 = (const float*)d_in[9];
    const float* b2  = (const float*)d_in[10];
    float* out = (float*)d_out;

    // ---- workspace layout (256B-aligned regions) ----
    char* p = (char*)d_ws;
    auto take = [&](size_t bytes) { char* r = p; p += (bytes + 255) & ~(size_t)255; return r; };
    int*   hist    = (int*)take((size_t)NCHUNK * NBUCKETS * 4);
    int*   bptr    = (int*)take((size_t)(NBUCKETS + 1) * 4);
    u32*   pairs   = (u32*)take((size_t)N_EDGES * 4);
    int*   csr_src = (int*)take((size_t)N_EDGES * 4);
    int*   row_ptr = (int*)take((size_t)N_NODES * 4);
    int*   cnt     = (int*)take((size_t)N_NODES * 4);
    float* inv     = (float*)take((size_t)N_NODES * 4);
    uint4* Bfrag   = (uint4*)take((size_t)3 * 16 * 64 * 16);
    u16*   xh      = (u16*)take((size_t)N_NODES * D * 2);
    u16*   h0h     = (u16*)take((size_t)N_NODES * D * 2);
    u16*   h1h     = (u16*)take((size_t)N_NODES * D * 2);

    const int BLK = 256;
    const int conv_grid  = (N_NODES * D / 4 + BLK - 1) / BLK;
    const int layer_grid = (N_NODES + 63) / 64;    // 64 nodes per block

    // ---- deterministic bucketed partition + CSR (zero global atomics) ----
    hist_kernel<<<NCHUNK, PBLK, 0, stream>>>(dst, hist);
    cscan_kernel<<<1, 1024, 0, stream>>>(hist, bptr);
    part_kernel<<<NCHUNK, PBLK, 0, stream>>>(src, dst, hist, pairs);
    local_csr_kernel<<<NBUCKETS, BLK, 0, stream>>>(pairs, bptr, row_ptr, cnt, inv, csr_src);
    tof16_kernel<<<conv_grid, BLK, 0, stream>>>(x, xh, N_NODES * D / 4);
    prep_bfrag<<<(3 * 1024 + BLK - 1) / BLK, BLK, 0, stream>>>(Wl0, Wr0, Wl1, Wr1, Wl2, Wr2, Bfrag);

    // ---- 3 fused layers (intermediates are f16-only) ----
    sage_layer<<<layer_grid, BLK, 0, stream>>>(xh,  row_ptr, cnt, csr_src, inv, Bfrag,        b0, nullptr, h0h, 1);
    sage_layer<<<layer_grid, BLK, 0, stream>>>(h0h, row_ptr, cnt, csr_src, inv, Bfrag + 1024, b1, nullptr, h1h, 1);
    sage_layer<<<layer_grid, BLK, 0, stream>>>(h1h, row_ptr, cnt, csr_src, inv, Bfrag + 2048, b2, out, nullptr, 0);
}